// Round 6
// baseline (262.643 us; speedup 1.0000x reference)
//
#include <hip/hip_runtime.h>

#define DIM   1024
#define HID   512
#define NEXP  16
#define TOPK  4
#define SLOTS 5
#define PITCH 72     // 64 + 8 bf16 pad: row stride 36 words -> 2-way bank alias (free, m136)
#define MAXT128 96   // sum ceil(c_e/128) <= 8192/128 + 16 + 2048/128 = 96

typedef unsigned short u16;
typedef unsigned int   u32;
typedef short bf16x8 __attribute__((ext_vector_type(8)));
typedef float f32x4  __attribute__((ext_vector_type(4)));

__device__ __forceinline__ float bf2f(u16 u) {
    union { u32 i; float f; } v; v.i = ((u32)u) << 16; return v.f;
}
__device__ __forceinline__ u16 f2bf(float f) {
    union { float f; u32 i; } v; v.f = f;
    u32 lsb = (v.i >> 16) & 1u;
    v.i += 0x7fffu + lsb;              // round-to-nearest-even
    return (u16)(v.i >> 16);
}
__device__ __forceinline__ uint4 pack8(float4 a, float4 b) {
    uint4 r;
    r.x = (u32)f2bf(a.x) | ((u32)f2bf(a.y) << 16);
    r.y = (u32)f2bf(a.z) | ((u32)f2bf(a.w) << 16);
    r.z = (u32)f2bf(b.x) | ((u32)f2bf(b.y) << 16);
    r.w = (u32)f2bf(b.z) | ((u32)f2bf(b.w) << 16);
    return r;
}

// segment boundaries (8-elem chunks) in the contiguous bf16 dst buffer:
// [w1 | sw1 | w3 | sw3 | w2 | sw2 | x]  -> W1c/W3c/W2c each get expert 16 = shared
#define CW ((size_t)NEXP * HID * DIM / 8)   // 1,048,576
#define CS ((size_t)HID * DIM / 8)          //    65,536
#define SEG_B0 (CW)
#define SEG_B1 (SEG_B0 + CS)
#define SEG_B2 (SEG_B1 + CW)
#define SEG_B3 (SEG_B2 + CS)
#define SEG_B4 (SEG_B3 + CW)
#define SEG_B5 (SEG_B4 + CS)                // 3,342,336 chunks (weights only)
// + x: T*DIM/8 = 262,144  -> total 3,604,480 chunks = 3520 blocks * 1024
#define CVT_BLKS 3520
#define RTR_BLKS 512                        // 4 router waves (tokens) per block

// ------------------------------------------------------------------- prep ---
// blocks [0, CVT_BLKS): fp32->bf16, 4 chunks/thread (8 independent loads in
// flight -> latency-hiding; R5's 1-chunk version was MLP-starved at 1.5 TB/s).
// blocks [CVT_BLKS, CVT_BLKS+RTR_BLKS): router, 1 wave per token.
__global__ __launch_bounds__(256) void moe_prep(
    const float* __restrict__ x,    const float* __restrict__ gate,
    const float* __restrict__ w1,   const float* __restrict__ w3,
    const float* __restrict__ w2,   const float* __restrict__ sw1,
    const float* __restrict__ sw3,  const float* __restrict__ sw2,
    u16* __restrict__ dst,
    int* __restrict__ counts, u32* __restrict__ pairs,
    float* __restrict__ wslot, int T)
{
    const int blk = blockIdx.x;
    const int tid = threadIdx.x;
    if (blk < CVT_BLKS) {
        size_t cc[4]; float4 A[4], B[4];
#pragma unroll
        for (int k = 0; k < 4; ++k) {
            const size_t c = (size_t)blk * 1024 + k * 256 + tid;
            cc[k] = c;
            const float* src; size_t loc;
            if      (c < SEG_B0) { src = w1;  loc = c; }
            else if (c < SEG_B1) { src = sw1; loc = c - SEG_B0; }
            else if (c < SEG_B2) { src = w3;  loc = c - SEG_B1; }
            else if (c < SEG_B3) { src = sw3; loc = c - SEG_B2; }
            else if (c < SEG_B4) { src = w2;  loc = c - SEG_B3; }
            else if (c < SEG_B5) { src = sw2; loc = c - SEG_B4; }
            else                 { src = x;   loc = c - SEG_B5; }
            A[k] = ((const float4*)src)[loc * 2];
            B[k] = ((const float4*)src)[loc * 2 + 1];
        }
#pragma unroll
        for (int k = 0; k < 4; ++k)
            ((uint4*)dst)[cc[k]] = pack8(A[k], B[k]);
        return;
    }
    // ---- router: wave wv of this block handles token t ----
    const int lane = tid & 63;
    const int t = (blk - CVT_BLKS) * 4 + (tid >> 6);
    if (t >= T) return;
    const float* xrow = x + (size_t)t * DIM;
    float xr[16];
#pragma unroll
    for (int j = 0; j < 16; ++j) xr[j] = xrow[lane + 64 * j];

    float logit[NEXP];
#pragma unroll
    for (int e = 0; e < NEXP; ++e) {
        const float* g = gate + (size_t)e * DIM;
        float s = 0.f;
#pragma unroll
        for (int j = 0; j < 16; ++j) s += xr[j] * g[lane + 64 * j];
#pragma unroll
        for (int off = 32; off > 0; off >>= 1) s += __shfl_xor(s, off);
        logit[e] = s;   // identical across lanes
    }
    float v[NEXP];
#pragma unroll
    for (int e = 0; e < NEXP; ++e) v[e] = logit[e];
    int idx[TOPK]; float lv[TOPK];
#pragma unroll
    for (int r = 0; r < TOPK; ++r) {                 // strict > : lax.top_k ties
        int be = 0; float bv = v[0];
        for (int e = 1; e < NEXP; ++e) { if (v[e] > bv) { bv = v[e]; be = e; } }
        idx[r] = be; lv[r] = bv; v[be] = -3.0e38f;
    }
    float wk[TOPK]; float wsum = 0.f;
#pragma unroll
    for (int r = 0; r < TOPK; ++r) { wk[r] = __expf(lv[r] - lv[0]); wsum += wk[r]; }
#pragma unroll
    for (int r = 0; r < TOPK; ++r) wk[r] /= wsum;

    if (lane < TOPK) {
        int e = idx[lane];
        int slot = atomicAdd(&counts[e], 1);
        if (slot < T) pairs[(size_t)e * T + slot] = ((u32)t << 3) | (u32)lane;
        wslot[t * SLOTS + lane] = wk[lane];
    } else if (lane == TOPK) {
        pairs[(size_t)NEXP * T + t] = ((u32)t << 3) | 4u;   // shared expert
        wslot[t * SLOTS + 4] = 1.0f;
    }
}

// ---------------------------------------------------- tile builder (1 wave) -
__global__ __launch_bounds__(64) void moe_build_tiles(
    const int* __restrict__ counts,
    int* __restrict__ tileE, int* __restrict__ tileR0, int* __restrict__ tileNV,
    int* __restrict__ tot, int T)
{
    const int lane = threadIdx.x;
    int c = 0;
    if (lane < NEXP)       c = min(max(counts[lane], 0), T);
    else if (lane == NEXP) c = T;
    int nt = (c + 127) >> 7;
    int pre = nt;                                   // inclusive prefix over lanes
    for (int off = 1; off < 32; off <<= 1) {
        int vv = __shfl_up(pre, off);
        if (lane >= off) pre += vv;
    }
    int excl = pre - nt;
    if (lane <= NEXP) {
        for (int i = 0; i < nt; ++i) {
            int id = excl + i;
            if (id < MAXT128) {
                tileE[id] = lane; tileR0[id] = i << 7;
                tileNV[id] = min(128, c - (i << 7));
            }
        }
        if (lane == NEXP) *tot = min(excl + nt, MAXT128);
    }
}

// ------------------------------------------------------------------ gemm1 ---
// 128x64x64 tiles: act[t*5+slot][0:512] = silu(x.W1_e^T) * (x.W3_e^T)
__global__ __launch_bounds__(256) void moe_gemm1(
    const u16* __restrict__ xb,
    const u16* __restrict__ w1c, const u16* __restrict__ w3c,
    const u32* __restrict__ pairs,
    const int* __restrict__ tileE, const int* __restrict__ tileR0,
    const int* __restrict__ tileNV, const int* __restrict__ tot,
    u16* __restrict__ act, int T)
{
    const int tile = blockIdx.y;
    if (tile >= min(*tot, MAXT128)) return;
    const int e  = min(max(tileE[tile], 0), NEXP);
    const int r0 = min(max(tileR0[tile], 0), T - 1);
    const int nv = min(max(tileNV[tile], 0), min(128, T - r0));
    const int n0 = blockIdx.x * 64;

    const u16* W1 = w1c + (size_t)e * HID * DIM;
    const u16* W3 = w3c + (size_t)e * HID * DIM;

    __shared__ __align__(16) u16 sA [128 * PITCH];
    __shared__ __align__(16) u16 sB1[ 64 * PITCH];
    __shared__ __align__(16) u16 sB3[ 64 * PITCH];
    __shared__ u32 sEnt[128];

    const int tid = threadIdx.x;
    if (tid < 128) {
        u32 ent = (tid < nv) ? pairs[(size_t)e * T + r0 + tid] : 0u;
        u32 tk = ent >> 3, sl = ent & 7u;
        if (tk >= (u32)T) tk = 0;
        if (sl >= SLOTS)  sl = 0;
        sEnt[tid] = (tk << 3) | sl;
    }
    __syncthreads();

    const int ar = tid >> 1;            // sA staging row 0..127
    const int ac = (tid & 1) * 32;      // 32 elems (4 uint4) per thread
    const u16* xrow = xb + (size_t)(sEnt[ar] >> 3) * DIM;
    const int br = tid >> 2;            // sB row 0..63
    const int bc = (tid & 3) * 16;      // 16 elems (2 uint4)
    const u16* b1row = W1 + (size_t)(n0 + br) * DIM;
    const u16* b3row = W3 + (size_t)(n0 + br) * DIM;

    const int wv   = tid >> 6;          // wave -> M rows [wv*32, wv*32+32)
    const int lane = tid & 63;
    const int l15  = lane & 15;
    const int kq   = (lane >> 4) * 8;
    const int m0   = wv * 32;

    f32x4 acc1[2][4], acc3[2][4];
#pragma unroll
    for (int i = 0; i < 2; ++i)
#pragma unroll
        for (int j = 0; j < 4; ++j) { acc1[i][j] = (f32x4){0,0,0,0}; acc3[i][j] = (f32x4){0,0,0,0}; }

    for (int kt = 0; kt < DIM; kt += 64) {
        __syncthreads();
        *(uint4*)&sA [ar*PITCH + ac]      = *(const uint4*)&xrow [kt + ac];
        *(uint4*)&sA [ar*PITCH + ac +  8] = *(const uint4*)&xrow [kt + ac +  8];
        *(uint4*)&sA [ar*PITCH + ac + 16] = *(const uint4*)&xrow [kt + ac + 16];
        *(uint4*)&sA [ar*PITCH + ac + 24] = *(const uint4*)&xrow [kt + ac + 24];
        *(uint4*)&sB1[br*PITCH + bc]      = *(const uint4*)&b1row[kt + bc];
        *(uint4*)&sB1[br*PITCH + bc +  8] = *(const uint4*)&b1row[kt + bc + 8];
        *(uint4*)&sB3[br*PITCH + bc]      = *(const uint4*)&b3row[kt + bc];
        *(uint4*)&sB3[br*PITCH + bc +  8] = *(const uint4*)&b3row[kt + bc + 8];
        __syncthreads();
#pragma unroll
        for (int ks = 0; ks < 64; ks += 32) {
            bf16x8 a0 = *(const bf16x8*)&sA[(m0      + l15)*PITCH + ks + kq];
            bf16x8 a1 = *(const bf16x8*)&sA[(m0 + 16 + l15)*PITCH + ks + kq];
#pragma unroll
            for (int nt = 0; nt < 4; ++nt) {
                bf16x8 b1 = *(const bf16x8*)&sB1[(nt*16 + l15)*PITCH + ks + kq];
                bf16x8 b3 = *(const bf16x8*)&sB3[(nt*16 + l15)*PITCH + ks + kq];
                acc1[0][nt] = __builtin_amdgcn_mfma_f32_16x16x32_bf16(a0, b1, acc1[0][nt], 0, 0, 0);
                acc1[1][nt] = __builtin_amdgcn_mfma_f32_16x16x32_bf16(a1, b1, acc1[1][nt], 0, 0, 0);
                acc3[0][nt] = __builtin_amdgcn_mfma_f32_16x16x32_bf16(a0, b3, acc3[0][nt], 0, 0, 0);
                acc3[1][nt] = __builtin_amdgcn_mfma_f32_16x16x32_bf16(a1, b3, acc3[1][nt], 0, 0, 0);
            }
        }
    }
    // C/D: col = lane&15, row = (lane>>4)*4 + reg   (m89-verified)
#pragma unroll
    for (int mf = 0; mf < 2; ++mf)
#pragma unroll
    for (int nt = 0; nt < 4; ++nt)
#pragma unroll
    for (int r = 0; r < 4; ++r) {
        int ml = m0 + mf*16 + (lane >> 4)*4 + r;
        if (ml < nv) {
            float h1 = acc1[mf][nt][r], h3 = acc3[mf][nt][r];
            float a = (h1 / (1.f + __expf(-h1))) * h3;       // silu(h1)*h3
            u32 ent = sEnt[ml];
            size_t sidx = (size_t)(ent >> 3) * SLOTS + (ent & 7u);
            act[sidx * HID + n0 + nt*16 + l15] = f2bf(a);
        }
    }
}

// ------------------------------------------------------------------ gemm2 ---
// 128x128x64 tiles. useEout: eout[sidx][col] = w*(act.W2^T) else atomic to out.
__global__ __launch_bounds__(256) void moe_gemm2(
    const u16* __restrict__ act, const u16* __restrict__ w2c,
    const u32* __restrict__ pairs, const float* __restrict__ wslot,
    const int* __restrict__ tileE, const int* __restrict__ tileR0,
    const int* __restrict__ tileNV, const int* __restrict__ tot,
    u16* __restrict__ eout, float* __restrict__ out, int useEout, int T)
{
    const int tile = blockIdx.y;
    if (tile >= min(*tot, MAXT128)) return;
    const int e  = min(max(tileE[tile], 0), NEXP);
    const int r0 = min(max(tileR0[tile], 0), T - 1);
    const int nv = min(max(tileNV[tile], 0), min(128, T - r0));
    const int n0 = blockIdx.x * 128;

    const u16* W2 = w2c + (size_t)e * DIM * HID;

    __shared__ __align__(16) u16 sA[128 * PITCH];
    __shared__ __align__(16) u16 sB[128 * PITCH];
    __shared__ u32 sEnt[128];

    const int tid = threadIdx.x;
    if (tid < 128) {
        u32 ent = (tid < nv) ? pairs[(size_t)e * T + r0 + tid] : 0u;
        u32 tk = ent >> 3, sl = ent & 7u;
        if (tk >= (u32)T) tk = 0;
        if (sl >= SLOTS)  sl = 0;
        sEnt[tid] = (tk << 3) | sl;
    }
    __syncthreads();

    const int ar = tid >> 1;
    const int ac = (tid & 1) * 32;
    const u32 entA = sEnt[ar];
    const u16* arow = act + ((size_t)(entA >> 3) * SLOTS + (entA & 7u)) * HID;
    const u16* brow = W2 + (size_t)(n0 + ar) * HID;

    const int wv   = tid >> 6;
    const int lane = tid & 63;
    const int l15  = lane & 15;
    const int kq   = (lane >> 4) * 8;
    const int m0   = (wv & 1) * 64;     // wave 2x2 grid over 128x128
    const int nc0  = (wv >> 1) * 64;

    f32x4 acc[4][4];
#pragma unroll
    for (int i = 0; i < 4; ++i)
#pragma unroll
        for (int j = 0; j < 4; ++j) acc[i][j] = (f32x4){0,0,0,0};

    for (int kt = 0; kt < HID; kt += 64) {
        __syncthreads();
        *(uint4*)&sA[ar*PITCH + ac]      = *(const uint4*)&arow[kt + ac];
        *(uint4*)&sA[ar*PITCH + ac +  8] = *(const uint4*)&arow[kt + ac +  8];
        *(uint4*)&sA[ar*PITCH + ac + 16] = *(const uint4*)&arow[kt + ac + 16];
        *(uint4*)&sA[ar*PITCH + ac + 24] = *(const uint4*)&arow[kt + ac + 24];
        *(uint4*)&sB[ar*PITCH + ac]      = *(const uint4*)&brow[kt + ac];
        *(uint4*)&sB[ar*PITCH + ac +  8] = *(const uint4*)&brow[kt + ac +  8];
        *(uint4*)&sB[ar*PITCH + ac + 16] = *(const uint4*)&brow[kt + ac + 16];
        *(uint4*)&sB[ar*PITCH + ac + 24] = *(const uint4*)&brow[kt + ac + 24];
        __syncthreads();
#pragma unroll
        for (int ks = 0; ks < 64; ks += 32) {
            bf16x8 af[4], bf[4];
#pragma unroll
            for (int mf = 0; mf < 4; ++mf)
                af[mf] = *(const bf16x8*)&sA[(m0 + mf*16 + l15)*PITCH + ks + kq];
#pragma unroll
            for (int nf = 0; nf < 4; ++nf)
                bf[nf] = *(const bf16x8*)&sB[(nc0 + nf*16 + l15)*PITCH + ks + kq];
#pragma unroll
            for (int mf = 0; mf < 4; ++mf)
#pragma unroll
                for (int nf = 0; nf < 4; ++nf)
                    acc[mf][nf] = __builtin_amdgcn_mfma_f32_16x16x32_bf16(af[mf], bf[nf], acc[mf][nf], 0, 0, 0);
        }
    }
#pragma unroll
    for (int mf = 0; mf < 4; ++mf)
#pragma unroll
    for (int nf = 0; nf < 4; ++nf)
#pragma unroll
    for (int r = 0; r < 4; ++r) {
        int ml = m0 + mf*16 + (lane >> 4)*4 + r;
        if (ml < nv) {
            u32 ent = sEnt[ml];
            u32 tk = ent >> 3;
            float cw = wslot[tk * SLOTS + (ent & 7u)];
            int col = n0 + nc0 + nf*16 + l15;
            float v = cw * acc[mf][nf][r];
            if (useEout) {
                size_t sidx = (size_t)tk * SLOTS + (ent & 7u);
                eout[sidx * DIM + col] = f2bf(v);
            } else {
                atomicAdd(&out[(size_t)tk * DIM + col], v);
            }
        }
    }
}

// ---------------------------------------------------------------- combine ---
// out[t][col..col+3] = sum_s eout[t*5+s][col..col+3]  (weights pre-applied)
__global__ __launch_bounds__(256) void moe_combine(
    const u16* __restrict__ eout, float* __restrict__ out, int n4)
{
    int i = blockIdx.x * 256 + threadIdx.x;
    if (i >= n4) return;
    int o4 = i * 4;
    int t = o4 >> 10;                   // DIM = 1024
    int col = o4 & 1023;
    float a0 = 0.f, a1 = 0.f, a2 = 0.f, a3 = 0.f;
#pragma unroll
    for (int s = 0; s < SLOTS; ++s) {
        const u16* row = eout + ((size_t)t * SLOTS + s) * DIM + col;
        ushort4 u = *(const ushort4*)row;
        a0 += bf2f(u.x); a1 += bf2f(u.y); a2 += bf2f(u.z); a3 += bf2f(u.w);
    }
    float4* op = (float4*)(out + (size_t)t * DIM + col);
    *op = (float4){a0, a1, a2, a3};
}

// ------------------------------------------------------------------ launch --
extern "C" void kernel_launch(void* const* d_in, const int* in_sizes, int n_in,
                              void* d_out, int out_size, void* d_ws, size_t ws_size,
                              hipStream_t stream)
{
    (void)n_in; (void)out_size;
    const float* x    = (const float*)d_in[0];
    const float* gate = (const float*)d_in[1];
    const float* w1   = (const float*)d_in[2];
    const float* w3   = (const float*)d_in[3];
    const float* w2   = (const float*)d_in[4];
    const float* sw1  = (const float*)d_in[5];
    const float* sw3  = (const float*)d_in[6];
    const float* sw2  = (const float*)d_in[7];
    float* out = (float*)d_out;
    const int T = in_sizes[0] / DIM;     // 2048

    char* w = (char*)d_ws;
    int*  counts = (int*)(w);            // 256 B zeroed each call
    int*  tileE  = (int*)(w + 256);
    int*  tileR0 = (int*)(w + 256 + 512);
    int*  tileNV = (int*)(w + 256 + 1024);
    int*  tot    = (int*)(w + 256 + 1536);
    size_t off = 4096;
    u32*   pairs = (u32*)(w + off);  off += (size_t)(NEXP + 1) * T * 4;   // 139 KB
    float* wslot = (float*)(w + off); off += (size_t)T * SLOTS * 4;       //  40 KB
    off = (off + 255) & ~(size_t)255;
    u16*   actb  = (u16*)(w + off);  off += (size_t)T * SLOTS * HID * 2;  // 10.5 MB
    off = (off + 255) & ~(size_t)255;
    u16*   cvtb  = (u16*)(w + off);
    const size_t xChunks = (size_t)T * DIM / 8;
    const size_t cvtChunks = SEG_B5 + xChunks;                            // 3,604,480
    off += cvtChunks * 8 * 2;                                             // 57.7 MB
    off = (off + 255) & ~(size_t)255;
    u16*   eoutb = (u16*)(w + off);
    const size_t needEout = off + (size_t)T * SLOTS * DIM * 2;            // ~89.4 MB

    u16* W1c = cvtb;                       // [17][HID][DIM] (sw1 = expert 16)
    u16* W3c = cvtb + SEG_B1 * 8;
    u16* W2c = cvtb + SEG_B3 * 8;
    u16* xb  = cvtb + SEG_B5 * 8;

    const int useEout = (ws_size >= needEout) ? 1 : 0;   // constant -> graph-safe

    hipMemsetAsync(w, 0, 256, stream);                   // counts
    if (!useEout)
        hipMemsetAsync(out, 0, (size_t)T * DIM * sizeof(float), stream);

    moe_prep<<<CVT_BLKS + RTR_BLKS, 256, 0, stream>>>(
        x, gate, w1, w3, w2, sw1, sw3, sw2, cvtb, counts, pairs, wslot, T);
    moe_build_tiles<<<1, 64, 0, stream>>>(counts, tileE, tileR0, tileNV, tot, T);

    moe_gemm1<<<dim3(HID / 64, MAXT128), 256, 0, stream>>>(
        xb, W1c, W3c, pairs, tileE, tileR0, tileNV, tot, actb, T);
    moe_gemm2<<<dim3(DIM / 128, MAXT128), 256, 0, stream>>>(
        actb, W2c, pairs, wslot, tileE, tileR0, tileNV, tot, eoutb, out, useEout, T);
    if (useEout)
        moe_combine<<<(T * DIM / 4 + 255) / 256, 256, 0, stream>>>(
            eoutb, out, T * DIM / 4);
}